// Round 6
// baseline (165.331 us; speedup 1.0000x reference)
//
#include <hip/hip_runtime.h>

typedef unsigned long long ull;

#define B_    128
#define T_    4096
#define V_    32
#define NHID  256
#define GDIM  2048            // V * 2 * 32
#define GW    0.25f

// ---------------------------------------------------------------------------
// K1: masks -> raw ballot bitmask words in global scratch.
// Block = (b, v-quarter(8 vars), T-quarter(1024 t)), 256 threads, no LDS.
// Thread (tl=tid>>1, vq=tid&1) loads int4 of vars vq4*8+vq*4.. at t.
// Ballot bit l of a word covers t-offset (l>>1), var parity (l&1).
// gm[((b*4+vq4)*4 + comp)*128 + word], word = t/32; bit(t,par) = 2*(t&31)+par.
// ---------------------------------------------------------------------------
__global__ __launch_bounds__(256) void mask_kernel(
    const int* __restrict__ masks, ull* __restrict__ gm)
{
    int bid = blockIdx.x;
    int wg  = (bid & 7) * 256 + (bid >> 3);   // XCD swizzle: siblings adjacent
    int vq4 = wg & 3;
    int tq  = (wg >> 2) & 3;
    int b   = wg >> 4;

    int tid = threadIdx.x, lane = tid & 63, wave = tid >> 6;
    int vq = tid & 1, tl = tid >> 1;          // tl in [0,128)

    const int* mbase = masks + ((long)b * T_) * V_ + vq4 * 8 + vq * 4;
    int wbase = (b * 4 + vq4) * 4 * 128 + tq * 32 + wave;

    int4 m[8];
    #pragma unroll
    for (int c = 0; c < 8; ++c)
        m[c] = *reinterpret_cast<const int4*>(mbase + (long)(tq*1024 + c*128 + tl) * V_);

    #pragma unroll
    for (int c = 0; c < 8; ++c) {
        ull bl0 = __ballot(m[c].x != 0);
        ull bl1 = __ballot(m[c].y != 0);
        ull bl2 = __ballot(m[c].z != 0);
        ull bl3 = __ballot(m[c].w != 0);
        if (lane < 4) {
            ull w = (lane == 0) ? bl0 : (lane == 1) ? bl1 : (lane == 2) ? bl2 : bl3;
            gm[wbase + lane * 128 + c * 4] = w;
        }
    }
}

// ---------------------------------------------------------------------------
// K2: per-block = (b, 4 vars of one parity). 256 threads (4 waves).
// Stage time row + 4 comps' bitmask words; wave w builds word-rank prefix for
// its var (popcount + shfl scan); then 1 query/thread:
//   p  = searchsorted(time_row, q)          (12 LDS probes)
//   r  = rank at p  (# valid with time < q) (== compacted searchsorted idx)
//   sel_l = last set bit < p, sel_r = first set bit >= p  (clamped)
// then 2 scattered vals loads + interp.
// ---------------------------------------------------------------------------
__global__ __launch_bounds__(256) void query_kernel(
    const float* __restrict__ vals, const float* __restrict__ time_,
    const ull* __restrict__ gm, const float* __restrict__ l_t,
    float* __restrict__ g_ws, float* __restrict__ mid_out)
{
    __shared__ float time_s[T_];              // 16 KB
    __shared__ ull   mask64[4][128];          // 4 KB
    __shared__ unsigned short rank16[4][128]; // 1 KB  (exclusive, per word)
    __shared__ int   nv_s[4];
    __shared__ float tmax_s[4];

    int bid = blockIdx.x;
    int wg  = (bid & 7) * 128 + (bid >> 3);   // co-locate all vgs of b per XCD
    int b   = wg >> 3;
    int vg  = wg & 7;
    int vq4 = vg >> 1, par = vg & 1;

    int tid = threadIdx.x, lane = tid & 63, wave = tid >> 6;

    {   // stage time (float4) and mask words
        const float4* t4 = (const float4*)(time_ + (long)b * T_);
        float4* s4 = (float4*)time_s;
        #pragma unroll
        for (int i = 0; i < 4; ++i) s4[tid + i * 256] = t4[tid + i * 256];
        const ull* src = gm + (long)(b * 4 + vq4) * 4 * 128;
        ((ull*)mask64)[tid]       = src[tid];
        ((ull*)mask64)[tid + 256] = src[tid + 256];
    }
    __syncthreads();

    ull pm = 0x5555555555555555ull << par;

    {   // rank scan: wave w handles its own var (comp w)
        ull w0 = mask64[wave][2*lane]     & pm;
        ull w1 = mask64[wave][2*lane + 1] & pm;
        int pa = __popcll(w0), pb = __popcll(w1);
        int x = pa + pb, inc = x;
        #pragma unroll
        for (int off = 1; off < 64; off <<= 1) {
            int y = __shfl_up(inc, off, 64);
            if (lane >= off) inc += y;
        }
        int excl = inc - x;
        rank16[wave][2*lane]     = (unsigned short)excl;
        rank16[wave][2*lane + 1] = (unsigned short)(excl + pa);
        if (lane == 63) nv_s[wave] = inc;
        ull nzball = __ballot((w0 | w1) != 0ull);
        if (nzball) {
            int hl = 63 - __clzll(nzball);
            if (lane == hl) {
                ull wsel = w1 ? w1 : w0;
                int widx = 2*lane + (w1 ? 1 : 0);
                int bp = 63 - __clzll(wsel);
                tmax_s[wave] = time_s[widx * 32 + (bp >> 1)];
            }
        }
    }
    __syncthreads();

    // ---- query: wave = var, lane = query j (G-major j = g*32+k) ----
    int v   = wave;
    int vgl = vq4 * 8 + par * 4 + v;
    int j   = lane, gs = j >> 5, k = j & 31;
    int nv  = nv_s[v];
    float outv = 0.0f;
    if (nv > 0) {
        float hw  = GW * (gs ? 5.0f : 1.0f) * 0.5f;
        float off = -hw + (float)k * (2.0f * hw / 31.0f);
        float qv  = (off + l_t[b]) * tmax_s[v];

        int lo = 0, hi = T_;                  // searchsorted 'left' on full row
        while (lo < hi) { int mid = (lo + hi) >> 1;
                          if (time_s[mid] < qv) lo = mid + 1; else hi = mid; }
        int p = lo;

        int r;                                 // rank = # valid with time < qv
        if (p >= T_) r = nv;
        else {
            int wr = p >> 5, tin = p & 31;
            ull below = tin ? ((1ull << (2 * tin)) - 1ull) : 0ull;
            r = (int)rank16[v][wr] + __popcll(mask64[v][wr] & pm & below);
        }

        int sel_l, sel_r;
        if (r >= nv) {
            // both endpoints clamp to last valid: prev set bit < p
            int wx; ull w;
            if (p >= T_) { wx = 127; w = mask64[v][127] & pm; }
            else {
                wx = p >> 5;
                int tin = p & 31;
                ull below = tin ? ((1ull << (2 * tin)) - 1ull) : 0ull;
                w = mask64[v][wx] & pm & below;
            }
            while (!w) { --wx; w = mask64[v][wx] & pm; }
            sel_l = sel_r = wx * 32 + ((63 - __clzll(w)) >> 1);
        } else if (r == 0) {
            // both endpoints clamp to first valid: next set bit >= p
            int wx = p >> 5;                  // r<nv => next exists => p<T_
            int tin = p & 31;
            ull below = tin ? ((1ull << (2 * tin)) - 1ull) : 0ull;
            ull w = mask64[v][wx] & pm & ~below;
            while (!w) { ++wx; w = mask64[v][wx] & pm; }
            sel_l = sel_r = wx * 32 + (__builtin_ctzll(w) >> 1);
        } else {
            int wx = p >> 5;
            int tin = p & 31;
            ull below = tin ? ((1ull << (2 * tin)) - 1ull) : 0ull;
            ull wb = mask64[v][wx] & pm & below;
            int wl = wx;
            while (!wb) { --wl; wb = mask64[v][wl] & pm; }
            sel_l = wl * 32 + ((63 - __clzll(wb)) >> 1);
            ull wa = mask64[v][wx] & pm & ~below;
            int wrx = wx;
            while (!wa) { ++wrx; wa = mask64[v][wrx] & pm; }
            sel_r = wrx * 32 + (__builtin_ctzll(wa) >> 1);
        }

        float tle = time_s[sel_l], tre = time_s[sel_r];
        float vle = vals[((long)b * T_ + sel_l) * V_ + vgl];
        float vre = vals[((long)b * T_ + sel_r) * V_ + vgl];
        float den = tre - tle;
        float wt  = (den > 0.0f) ? (qv - tle) / den : 0.0f;
        outv = vle + wt * (vre - vle);
    }
    int col = vgl * 64 + j;
    g_ws[(long)b * GDIM + col] = outv;
    if (col == 1024) mid_out[b] = outv;       // g[:, 1024]
}

// ---------------------------------------------------------------------------
// K3: grep = [g, l_t] @ W^T + bias. 1024 blocks (16 bg x 64 hg), 4 waves.
// Wave holds 2 b-rows of g as float4 regs; W rows read coalesced, shared
// across the 16 bg siblings on one XCD.
// ---------------------------------------------------------------------------
__global__ __launch_bounds__(256) void grep_kernel(
    const float* __restrict__ g_ws, const float* __restrict__ l_t,
    const float* __restrict__ W, const float* __restrict__ bias,
    float* __restrict__ out)
{
    int bid = blockIdx.x;
    int wg = (bid & 7) * 128 + (bid >> 3);
    int hg = wg >> 4;                        // 64 groups of 4 h
    int bg = wg & 15;                        // 16 groups of 8 b
    int tid = threadIdx.x, lane = tid & 63, wave = tid >> 6;
    int b0 = bg * 8 + wave * 2;
    int h0 = hg * 4;

    float4 ga[2][8];
    #pragma unroll
    for (int i = 0; i < 2; ++i)
        #pragma unroll
        for (int c = 0; c < 8; ++c)
            ga[i][c] = *(const float4*)(g_ws + (long)(b0 + i) * GDIM + c * 256 + lane * 4);
    float lt0 = l_t[b0], lt1 = l_t[b0 + 1];

    #pragma unroll
    for (int hh = 0; hh < 4; ++hh) {
        int h = h0 + hh;
        const float* wr = W + (long)h * (GDIM + 1);
        float a0 = 0.f, a1 = 0.f;
        #pragma unroll
        for (int c = 0; c < 8; ++c) {
            const float* wp = wr + c * 256 + lane * 4;
            float w0 = wp[0], w1 = wp[1], w2 = wp[2], w3 = wp[3];
            a0 += w0*ga[0][c].x + w1*ga[0][c].y + w2*ga[0][c].z + w3*ga[0][c].w;
            a1 += w0*ga[1][c].x + w1*ga[1][c].y + w2*ga[1][c].z + w3*ga[1][c].w;
        }
        if (lane == 0) { float wl = wr[GDIM]; a0 += wl * lt0; a1 += wl * lt1; }
        #pragma unroll
        for (int s = 32; s; s >>= 1) {
            a0 += __shfl_xor(a0, s, 64);
            a1 += __shfl_xor(a1, s, 64);
        }
        if (lane == 0) {
            float bv = bias[h];
            out[(long)(b0 + 0) * NHID + h] = a0 + bv;
            out[(long)(b0 + 1) * NHID + h] = a1 + bv;
        }
    }
}

extern "C" void kernel_launch(void* const* d_in, const int* in_sizes, int n_in,
                              void* d_out, int out_size, void* d_ws, size_t ws_size,
                              hipStream_t stream)
{
    const float* vals  = (const float*)d_in[0];
    const float* time_ = (const float*)d_in[1];
    const int*   masks = (const int*)d_in[2];
    // d_in[3] = lengths (unused by the reference outputs)
    const float* l_t   = (const float*)d_in[4];
    const float* W     = (const float*)d_in[5];
    const float* bias  = (const float*)d_in[6];

    float* out  = (float*)d_out;                       // [B*NHID] grep, then [B] mid
    float* g_ws = (float*)d_ws;                        // 1 MB: g [B, GDIM]
    ull*   gm   = (ull*)((char*)d_ws + (1 << 20));     // 2 MB: bitmask words

    mask_kernel <<<2048, 256, 0, stream>>>(masks, gm);
    query_kernel<<<1024, 256, 0, stream>>>(vals, time_, gm, l_t,
                                           g_ws, out + (long)B_ * NHID);
    grep_kernel <<<1024, 256, 0, stream>>>(g_ws, l_t, W, bias, out);
}